// Round 1
// 289.638 us; speedup vs baseline: 1.1049x; 1.1049x over previous
//
#include <hip/hip_runtime.h>
#include <hip/hip_bf16.h>

constexpr int NS   = 32;
constexpr int C    = 16;
constexpr int H    = 128;
constexpr int W    = 128;
constexpr int DS   = 5;
constexpr int M    = C * DS * DS;   // 400
constexpr int NLAG = 81;

typedef short short8 __attribute__((ext_vector_type(8)));
typedef float f32x4 __attribute__((ext_vector_type(4)));

// bf16 staging layout: xb[zi][n][row][ch][160] ushort:
//   [8 zero][128 data][8 zero][16 zero pad]  -> row-chunk = 16ch*160*2 = 5120 B
constexpr int CH_U    = 160;
constexpr int SLOT_U  = 16 * CH_U;            // 2560 us = 5120 B per row-slot
constexpr int SLOT_B  = SLOT_U * 2;
constexpr int RING_B  = 16 * SLOT_B;          // 81920 B
constexpr size_t XB_US_PER_IN = (size_t)NS * H * 16 * CH_U;   // 10,485,760

__device__ __forceinline__ unsigned int pk_bf16(float a, float b) {
    union { __hip_bfloat162 h; unsigned int u; } cv;
    cv.h = __float22bfloat162_rn(make_float2(a, b));
    return cv.u;
}

__device__ __forceinline__ void gl_lds16(const void* g, void* l) {
    __builtin_amdgcn_global_load_lds(
        (const __attribute__((address_space(1))) unsigned int*)g,
        (__attribute__((address_space(3))) unsigned int*)l, 16, 0, 0);
}

// ---------------------------------------------------------------------------
// prep kernel: blocks 0..1023 convert x->xb (bf16 halo layout);
// blocks 1024..2047 compute crosscorr P.
// Crosscorr uses the y-centric framing  P[u,v] = sum_r sum_w y[r-u+2,w] x[r,w+v-2]
// with a rolling 5-row y window in registers: 4 float4 loads per 100 FMAs
// (vs 16 loads per 100 FMAs in the h-centric version) and single-pass x reads.
// ---------------------------------------------------------------------------
__global__ __launch_bounds__(256, 1)
void prep_kernel(const float* __restrict__ x1, const float* __restrict__ x2,
                 const float* __restrict__ y1, const float* __restrict__ y2,
                 unsigned short* __restrict__ xb,
                 float* __restrict__ P1, float* __restrict__ P2)
{
    const int b = blockIdx.x, tid = threadIdx.x;
    if (b < 1024) {
        const int n = b & 31, zi = (b >> 5) & 1, rg = b >> 6;
        const float* xn = (zi ? x2 : x1) + (size_t)n * C * H * W;
        uint4* dst = (uint4*)(xb + (size_t)zi * XB_US_PER_IN +
                              ((size_t)n * H) * SLOT_U);
        for (int f = tid; f < 8 * 16 * 20; f += 256) {
            const int rc = f / 20, g = f - rc * 20;
            const int row = rg * 8 + (rc >> 4), ch = rc & 15;
            uint4 o = make_uint4(0u, 0u, 0u, 0u);
            if (g >= 1 && g <= 16) {
                const float4* s4 = (const float4*)(xn + ((size_t)ch * H + row) * W + (g - 1) * 8);
                float4 va = s4[0], vb = s4[1];
                o.x = pk_bf16(va.x, va.y); o.y = pk_bf16(va.z, va.w);
                o.z = pk_bf16(vb.x, vb.y); o.w = pk_bf16(vb.z, vb.w);
            }
            dst[((size_t)row * 16 + ch) * 20 + g] = o;
        }
        return;
    }
    const int b2 = b - 1024;
    const int n = b2 & 31, j = (b2 >> 5) & 15, zi = b2 >> 9;
    const float* x = zi ? x2 : x1;
    const float* y = zi ? y2 : y1;
    float* P       = zi ? P2 : P1;

    const float* yn = y + (size_t)n * H * W;
    const float* xc = x + ((size_t)n * C + j) * H * W;

    // 256 threads = 32 column-chunks (wg) x 8 row-slabs of 16 rows.
    const int wg = tid & 31, slab = tid >> 5;
    const int r0 = slab * 16;

    float acc[25];
#pragma unroll
    for (int l = 0; l < 25; ++l) acc[l] = 0.f;

    // rolling window: yw[u] = y[r + 2 - u] (float4 at columns wg*4..wg*4+3).
    // Initialize as if r = r0 - 1 (i.e. yw[u] = row r0+1-u); loop shifts first.
    float4 yw[5];
#pragma unroll
    for (int u = 0; u < 5; ++u) {
        const int t = r0 + 1 - u;
        yw[u] = (t >= 0) ? *(const float4*)(yn + (size_t)t * W + wg * 4)
                         : make_float4(0.f, 0.f, 0.f, 0.f);
    }

#pragma unroll 4
    for (int rr = 0; rr < 16; ++rr) {
        const int r = r0 + rr;
        // shift window down one row, bring in row r+2 (zero past bottom edge)
#pragma unroll
        for (int u = 4; u >= 1; --u) yw[u] = yw[u - 1];
        const int tnew = r + 2;
        yw[0] = (tnew < H) ? *(const float4*)(yn + (size_t)tnew * W + wg * 4)
                           : make_float4(0.f, 0.f, 0.f, 0.f);

        // x window for this row: columns wg*4-4 .. wg*4+7 (zero at w edges)
        const float* xr = xc + (size_t)r * W + wg * 4;
        float w12[12];
        float4 t4 = (wg > 0) ? *(const float4*)(xr - 4) : make_float4(0, 0, 0, 0);
        w12[0] = t4.x; w12[1] = t4.y; w12[2] = t4.z; w12[3] = t4.w;
        t4 = *(const float4*)(xr);
        w12[4] = t4.x; w12[5] = t4.y; w12[6] = t4.z; w12[7] = t4.w;
        t4 = (wg < 31) ? *(const float4*)(xr + 4) : make_float4(0, 0, 0, 0);
        w12[8] = t4.x; w12[9] = t4.y; w12[10] = t4.z; w12[11] = t4.w;

#pragma unroll
        for (int u = 0; u < 5; ++u) {
#pragma unroll
            for (int v = 0; v < 5; ++v)
                acc[u * 5 + v] += yw[u].x * w12[2 + v] + yw[u].y * w12[3 + v] +
                                  yw[u].z * w12[4 + v] + yw[u].w * w12[5 + v];
        }
    }

    __shared__ float red[4][25];
    const int lane = tid & 63, wv = tid >> 6;
#pragma unroll
    for (int l = 0; l < 25; ++l) {
        float v = acc[l];
#pragma unroll
        for (int off = 32; off; off >>= 1) v += __shfl_down(v, off);
        if (lane == 0) red[wv][l] = v;
    }
    __syncthreads();
    if (tid < 25)
        P[((size_t)n * C + j) * 25 + tid] = red[0][tid] + red[1][tid] + red[2][tid] + red[3][tid];
}

// ---------------------------------------------------------------------------
// MFMA autocorr: grid (n, zi, ug:4), 512 threads (8 waves).
// ---------------------------------------------------------------------------
template<int P0, int P1>
__device__ __forceinline__ void autocorr_body(const unsigned short* __restrict__ xn,
                                              float* __restrict__ Rn,
                                              char* sm, int tid)
{
    constexpr int U0 = P0 / 9;
    constexpr int U1 = (P1 - 1) / 9;
    constexpr int NB = U1 - U0 + 1;
    constexpr int NP = P1 - P0;

    unsigned short* ring = (unsigned short*)sm;
    const int lane = tid & 63;
    const int wid  = tid >> 6;
    const int q    = lane >> 4;
    const int mi   = lane & 15;
    const int rh   = wid & 3;
    const int chh  = wid >> 2;

    f32x4 acc[NP];
#pragma unroll
    for (int l = 0; l < NP; ++l) acc[l] = (f32x4){0.f, 0.f, 0.f, 0.f};

    const char* gb = (const char*)xn;

    for (int f = tid; f < 4 * 320; f += 512)
        ((uint4*)sm)[(12 + f / 320) * 320 + (f % 320)] = make_uint4(0, 0, 0, 0);
    for (int f = wid; f < 40; f += 8) {
        const int row = f / 5, e = f - row * 5;
        gl_lds16(gb + (size_t)row * SLOT_B + e * 1024 + lane * 16,
                 sm + row * SLOT_B + e * 1024);
    }
    __syncthreads();

    for (int s = 0; s < H; s += 4) {
        if (s < H - 8) {
            for (int f = wid; f < 20; f += 8) {
                const int row = s + 8 + f / 5, e = f - (f / 5) * 5;
                gl_lds16(gb + (size_t)row * SLOT_B + e * 1024 + lane * 16,
                         sm + (row & 15) * SLOT_B + e * 1024);
            }
        } else {
            for (int f = tid; f < 4 * 320; f += 512)
                ((uint4*)sm)[(((s + 8 + f / 320) & 15)) * 320 + (f % 320)] = make_uint4(0, 0, 0, 0);
        }

        const int r = s + rh;
        const unsigned short* rowA = ring + (r & 15) * SLOT_U + mi * CH_U;
#pragma unroll
        for (int cc = 0; cc < 2; ++cc) {
            const int w0 = (chh * 2 + cc) * 32;
            const uint4* pa = (const uint4*)(rowA + w0 + 8 * q);
            uint4 A0 = pa[0], A1 = pa[1], A2 = pa[2];
            unsigned int d[12] = {A0.x, A0.y, A0.z, A0.w, A1.x, A1.y, A1.z, A1.w,
                                  A2.x, A2.y, A2.z, A2.w};
            short8 bf[NB];
#pragma unroll
            for (int u = U0; u <= U1; ++u)
                bf[u - U0] = *(const short8*)(ring + ((r + u - 4 + 16) & 15) * SLOT_U +
                                              mi * CH_U + 8 + w0 + 8 * q);
#pragma unroll
            for (int v = 0; v < 9; ++v) {
                const int off = 12 - v;
                const int q4  = off >> 1;
                union { unsigned int u4[4]; short8 s8; } af;
                if (off & 1) {
#pragma unroll
                    for (int k2 = 0; k2 < 4; ++k2)
                        af.u4[k2] = (d[q4 + k2] >> 16) | (d[q4 + k2 + 1] << 16);
                } else {
#pragma unroll
                    for (int k2 = 0; k2 < 4; ++k2) af.u4[k2] = d[q4 + k2];
                }
#pragma unroll
                for (int u = U0; u <= U1; ++u) {
                    if (u * 9 + v >= P0 && u * 9 + v < P1)
                        acc[u * 9 + v - P0] = __builtin_amdgcn_mfma_f32_16x16x32_bf16(
                            af.s8, bf[u - U0], acc[u * 9 + v - P0], 0, 0, 0);
                }
            }
        }
        __syncthreads();
    }

    float* sred = (float*)sm;
#pragma unroll
    for (int cb = 0; cb < NP; cb += 9) {
        const int nc = (NP - cb < 9) ? (NP - cb) : 9;
        __syncthreads();
#pragma unroll
        for (int pp = 0; pp < 9; ++pp) {
            if (pp < nc) {
#pragma unroll
                for (int rg = 0; rg < 4; ++rg)
                    sred[(pp * 8 + wid) * 256 + (q * 4 + rg) * 16 + mi] = acc[cb + pp][rg];
            }
        }
        __syncthreads();
        if (tid < 256) {
#pragma unroll
            for (int pp = 0; pp < 9; ++pp) {
                if (pp < nc) {
                    float ssum = 0.f;
#pragma unroll
                    for (int w8 = 0; w8 < 8; ++w8)
                        ssum += sred[(pp * 8 + w8) * 256 + tid];
                    Rn[(size_t)tid * NLAG + P0 + cb + pp] = ssum;
                }
            }
        }
    }
}

__global__ __launch_bounds__(512, 2)
void autocorr_mfma(const unsigned short* __restrict__ xb,
                   float* __restrict__ R1, float* __restrict__ R2)
{
    __shared__ __align__(16) char sm[RING_B];
    const int n = blockIdx.x, zi = blockIdx.y, ug = blockIdx.z;
    const unsigned short* xn = xb + (size_t)zi * XB_US_PER_IN + (size_t)n * H * SLOT_U;
    float* Rn = (zi ? R2 : R1) + (size_t)n * C * C * NLAG;
    switch (ug) {
        case 0:  autocorr_body< 0, 20>(xn, Rn, sm, threadIdx.x); break;
        case 1:  autocorr_body<20, 40>(xn, Rn, sm, threadIdx.x); break;
        case 2:  autocorr_body<40, 60>(xn, Rn, sm, threadIdx.x); break;
        default: autocorr_body<60, 81>(xn, Rn, sm, threadIdx.x); break;
    }
}

// ---------------------------------------------------------------------------
// fused solve: CG1 (3 it) + CG2 (7 it) + 6-layer CNN, one block per sample.
// R block lives in LDS (flat layout Rl[t*81+l]; 81%32=17 coprime -> 64 distinct
// banks on reads); staged via async global_load_lds (linear copy). No big
// register arrays -> no spill / no per-iter global re-reads (R6 failure mode).
// ---------------------------------------------------------------------------
__device__ __forceinline__ float block_sum512(float v, float* red, int tid)
{
#pragma unroll
    for (int off = 32; off; off >>= 1) v += __shfl_down(v, off);
    if ((tid & 63) == 0) red[tid >> 6] = v;
    __syncthreads();
    float s = red[0] + red[1] + red[2] + red[3] + red[4] + red[5] + red[6] + red[7];
    __syncthreads();
    return s;
}

__device__ __forceinline__ float cg_solve(const float* __restrict__ Rrow, float rhs,
                                          int iters, float a, int t,
                                          float* pv, float* ap, float* red)
{
    const int jj = t & 15;
    float zreg = 0.f, rreg = 0.f, pmine = 0.f;
    if (t < M) {
        rreg = rhs; pmine = rhs;
        pv[(t / 25) * 28 + (t % 25)] = rhs;
    }
    float rr = block_sum512((t < M) ? rreg * rreg : 0.f, red, t);

    for (int it = 0; it < iters; ++it) {
        if (t < 256) {
            float pld[25], acc[25];
            const float* pj = &pv[jj * 28];
#pragma unroll
            for (int k = 0; k < 25; ++k) pld[k] = pj[k];
#pragma unroll
            for (int k = 0; k < 25; ++k) acc[k] = 0.f;
#pragma unroll
            for (int u = 0; u < 9; ++u) {
#pragma unroll
                for (int v = 0; v < 9; ++v) {
                    const float Rv = Rrow[u * 9 + v];      // LDS scalar read
#pragma unroll
                    for (int c = 0; c < 5; ++c) {
                        if (c < u - 4 || c > u) continue;
                        const int aa = 4 + c - u;
#pragma unroll
                        for (int dd = 0; dd < 5; ++dd) {
                            if (dd < v - 4 || dd > v) continue;
                            const int bb = 4 + dd - v;
                            acc[aa * 5 + bb] += Rv * pld[c * 5 + dd];
                        }
                    }
                }
            }
#pragma unroll
            for (int k = 0; k < 25; ++k) {
                float s2 = acc[k];
                s2 += __shfl_down(s2, 8, 16);
                s2 += __shfl_down(s2, 4, 16);
                s2 += __shfl_down(s2, 2, 16);
                s2 += __shfl_down(s2, 1, 16);
                acc[k] = s2;
            }
            if (jj == 0) {
#pragma unroll
                for (int k = 0; k < 25; ++k) ap[(t >> 4) * 25 + k] = acc[k];
            }
        }
        __syncthreads();
        float apv = 0.f;
        if (t < M) apv = ap[t] + a * pmine;
        float pAp = block_sum512((t < M) ? pmine * apv : 0.f, red, t);
        float al  = (pAp > 1e-30f) ? rr / pAp : 0.f;
        if (t < M) { zreg += al * pmine; rreg -= al * apv; }
        float rrn = block_sum512(rreg * rreg, red, t);
        float be  = (rr > 1e-30f) ? rrn / rr : 0.f;
        rr = rrn;
        if (t < M) {
            pmine = rreg + be * pmine;
            pv[(t / 25) * 28 + (t % 25)] = pmine;
        }
        __syncthreads();
    }
    return zreg;
}

__global__ __launch_bounds__(512, 1)
void solve_kernel(const float* __restrict__ R1, const float* __restrict__ R2,
                  const float* __restrict__ P1, const float* __restrict__ P2,
                  const float* __restrict__ d0, const float* __restrict__ alpha,
                  const float* __restrict__ beta, const float* __restrict__ reg,
                  const float* __restrict__ w1, const float* __restrict__ b1,
                  const float* __restrict__ w2, const float* __restrict__ b2,
                  const float* __restrict__ w3, const float* __restrict__ b3,
                  const float* __restrict__ w4, const float* __restrict__ b4,
                  const float* __restrict__ w5, const float* __restrict__ b5,
                  const float* __restrict__ w6, const float* __restrict__ b6,
                  float* __restrict__ out)
{
    __shared__ __align__(16) float Rl[256 * NLAG];   // 82944 B
    __shared__ float pv[16 * 28];
    __shared__ float ap[M];
    __shared__ float red[8];
    __shared__ float h0p[25 * 20];
    __shared__ float bufA[25 * 20], bufB[25 * 20];
    __shared__ float wl[16 * 9 * 20];
    __shared__ float bl[16];

    const int n = blockIdx.x, t = threadIdx.x;
    const float a = alpha[n] * (float)(H * W) * reg[0] / (float)(DS * DS * C);

    // stage R1 -> LDS (flat linear, async dma)
    {
        const char* g = (const char*)(R1 + (size_t)n * 256 * NLAG);
        char* l = (char*)Rl;
        for (int f = t; f < 256 * NLAG / 4; f += 512)
            gl_lds16(g + (size_t)f * 16, l + (size_t)f * 16);
    }
    float rhs1 = 0.f;
    if (t < M) rhs1 = P1[(size_t)n * M + t] + a * d0[(size_t)n * M + t];
    __syncthreads();   // drains the DMA
    float z1 = cg_solve(&Rl[(t & 255) * NLAG], rhs1, 3, a, t, pv, ap, red);

    __syncthreads();   // all reads of Rl done
    {
        const char* g = (const char*)(R2 + (size_t)n * 256 * NLAG);
        char* l = (char*)Rl;
        for (int f = t; f < 256 * NLAG / 4; f += 512)
            gl_lds16(g + (size_t)f * 16, l + (size_t)f * 16);
    }
    float rhs2 = 0.f;
    if (t < M) rhs2 = P2[(size_t)n * M + t] + a * z1;
    __syncthreads();
    float z2 = cg_solve(&Rl[(t & 255) * NLAG], rhs2, 7, a, t, pv, ap, red);

    // ---- CNN. Activations [pix][ch] pitch 20; weights [o*9+kk][ci] pitch 20.
    if (t < M) h0p[(t % 25) * 20 + t / 25] = z2;
    if (t < 25) h0p[t * 20 + 16] = rsqrtf(beta[n]);
    __syncthreads();

    const float* wsl[6] = {w1, w2, w3, w4, w5, w6};
    const float* bsl[6] = {b1, b2, b3, b4, b5, b6};

    for (int l = 0; l < 6; ++l) {
        const int cin = (l == 0) ? 17 : 16;
        for (int f = t; f < 16 * cin * 9; f += 512) {
            const int o = f / (cin * 9);
            const int rm = f - o * cin * 9;
            const int ci = rm / 9, kk = rm - ci * 9;
            wl[(o * 9 + kk) * 20 + ci] = wsl[l][f];
        }
        if (t < 16) bl[t] = bsl[l][t];
        __syncthreads();

        const float* act = (l == 0) ? h0p : ((l & 1) ? bufA : bufB);
        float s = 0.f;
        if (t < 400) {
            const int o = t / 25, pix = t % 25, yy = pix / 5, xx = pix % 5;
            s = bl[o];
#pragma unroll
            for (int ky = 0; ky < 3; ++ky) {
                const int iy = yy + ky - 1;
                if ((unsigned)iy >= 5u) continue;
#pragma unroll
                for (int kx = 0; kx < 3; ++kx) {
                    const int ix = xx + kx - 1;
                    if ((unsigned)ix >= 5u) continue;
                    const float* ip = act + (iy * 5 + ix) * 20;
                    const float* wp = wl + (o * 9 + ky * 3 + kx) * 20;
                    const float4 a0 = *(const float4*)(ip);
                    const float4 a1 = *(const float4*)(ip + 4);
                    const float4 a2 = *(const float4*)(ip + 8);
                    const float4 a3 = *(const float4*)(ip + 12);
                    const float4 q0 = *(const float4*)(wp);
                    const float4 q1 = *(const float4*)(wp + 4);
                    const float4 q2 = *(const float4*)(wp + 8);
                    const float4 q3 = *(const float4*)(wp + 12);
                    s += a0.x * q0.x + a0.y * q0.y + a0.z * q0.z + a0.w * q0.w
                       + a1.x * q1.x + a1.y * q1.y + a1.z * q1.z + a1.w * q1.w
                       + a2.x * q2.x + a2.y * q2.y + a2.z * q2.z + a2.w * q2.w
                       + a3.x * q3.x + a3.y * q3.y + a3.z * q3.z + a3.w * q3.w;
                    if (l == 0) s += ip[16] * wp[16];
                }
            }
            if (l < 5) s = fmaxf(s, 0.f);
            else       s += h0p[(t % 25) * 20 + t / 25];
        }
        __syncthreads();
        if (t < 400) {
            if (l == 5) out[(size_t)n * M + t] = s;
            else {
                float* dstb = (l & 1) ? bufB : bufA;
                dstb[(t % 25) * 20 + t / 25] = s;
            }
        }
        __syncthreads();
    }
}

// ---------------------------------------------------------------------------
extern "C" void kernel_launch(void* const* d_in, const int* in_sizes, int n_in,
                              void* d_out, int out_size, void* d_ws, size_t ws_size,
                              hipStream_t stream)
{
    (void)in_sizes; (void)n_in; (void)out_size; (void)ws_size;
    const float* x1    = (const float*)d_in[0];
    const float* x2    = (const float*)d_in[1];
    const float* d0    = (const float*)d_in[2];
    const float* y1    = (const float*)d_in[3];
    const float* y2    = (const float*)d_in[4];
    const float* alpha = (const float*)d_in[5];
    const float* beta  = (const float*)d_in[6];
    const float* reg   = (const float*)d_in[7];
    const float* w1 = (const float*)d_in[8];  const float* b1 = (const float*)d_in[9];
    const float* w2 = (const float*)d_in[10]; const float* b2 = (const float*)d_in[11];
    const float* w3 = (const float*)d_in[12]; const float* b3 = (const float*)d_in[13];
    const float* w4 = (const float*)d_in[14]; const float* b4 = (const float*)d_in[15];
    const float* w5 = (const float*)d_in[16]; const float* b5 = (const float*)d_in[17];
    const float* w6 = (const float*)d_in[18]; const float* b6 = (const float*)d_in[19];
    float* out = (float*)d_out;

    char* wsb = (char*)d_ws;
    unsigned short* xb = (unsigned short*)wsb;                 // 41.9 MB
    float* R1 = (float*)(wsb + 2 * XB_US_PER_IN * 2);
    const size_t RSZ = (size_t)NS * C * C * NLAG;              // 663552 floats
    float* R2 = R1 + RSZ;
    float* P1 = R2 + RSZ;
    float* P2 = P1 + (size_t)NS * M;

    prep_kernel<<<2048, 256, 0, stream>>>(x1, x2, y1, y2, xb, P1, P2);
    autocorr_mfma<<<dim3(NS, 2, 4), 512, 0, stream>>>(xb, R1, R2);
    solve_kernel<<<NS, 512, 0, stream>>>(R1, R2, P1, P2, d0, alpha, beta, reg,
                                         w1, b1, w2, b2, w3, b3, w4, b4,
                                         w5, b5, w6, b6, out);
}

// Round 3
// 265.772 us; speedup vs baseline: 1.2041x; 1.0898x over previous
//
#include <hip/hip_runtime.h>
#include <hip/hip_bf16.h>

constexpr int NS   = 32;
constexpr int C    = 16;
constexpr int H    = 128;
constexpr int W    = 128;
constexpr int DS   = 5;
constexpr int M    = C * DS * DS;   // 400
constexpr int NLAG = 81;

typedef short short8 __attribute__((ext_vector_type(8)));
typedef float f32x4 __attribute__((ext_vector_type(4)));

// bf16 staging layout: xb[zi][n][row][ch][152] ushort:
//   [8 zero][128 data][16 zero]  -> row-chunk = 16ch*152*2 = 4864 B
// CH_U=152 -> channel stride 304 B = 76 dwords == 12 (mod 32); within a
// 16-lane quarter-wave the b128 starts mi*12 mod 32 cover 8 distinct 4-bank
// groups, 2 lanes each -> 2-way (free) instead of the 8-way conflict that
// CH_U=160 (stride==16 mod 32) produced (1.66e7 conflict cycles/dispatch).
// Staging uses ONLY 16-byte global_load_lds (verified semantics): the ring
// slots are linear, and each stage region (8 rows init / 4 rows prefetch)
// is contiguous in both global and LDS -> whole-region 1024B wave-chunks.
constexpr int CH_U    = 152;
constexpr int SLOT_U  = 16 * CH_U;            // 2432 us = 4864 B per row-slot
constexpr int SLOT_B  = SLOT_U * 2;           // 4864
constexpr int RING_B  = 16 * SLOT_B;          // 77824 B
constexpr int CHK     = 19;                   // uint4 chunks per (row,ch) = 304 B
constexpr size_t XB_US_PER_IN = (size_t)NS * H * 16 * CH_U;   // 9,961,472

__device__ __forceinline__ unsigned int pk_bf16(float a, float b) {
    union { __hip_bfloat162 h; unsigned int u; } cv;
    cv.h = __float22bfloat162_rn(make_float2(a, b));
    return cv.u;
}

__device__ __forceinline__ void gl_lds16(const void* g, void* l) {
    __builtin_amdgcn_global_load_lds(
        (const __attribute__((address_space(1))) unsigned int*)g,
        (__attribute__((address_space(3))) unsigned int*)l, 16, 0, 0);
}

// ---------------------------------------------------------------------------
// prep kernel: blocks 0..1023 convert x->xb (bf16 halo layout);
// blocks 1024..2047 compute crosscorr P (y-centric rolling-window framing).
// ---------------------------------------------------------------------------
__global__ __launch_bounds__(256, 1)
void prep_kernel(const float* __restrict__ x1, const float* __restrict__ x2,
                 const float* __restrict__ y1, const float* __restrict__ y2,
                 unsigned short* __restrict__ xb,
                 float* __restrict__ P1, float* __restrict__ P2)
{
    const int b = blockIdx.x, tid = threadIdx.x;
    if (b < 1024) {
        const int n = b & 31, zi = (b >> 5) & 1, rg = b >> 6;
        const float* xn = (zi ? x2 : x1) + (size_t)n * C * H * W;
        uint4* dst = (uint4*)(xb + (size_t)zi * XB_US_PER_IN +
                              ((size_t)n * H) * SLOT_U);
        for (int f = tid; f < 8 * 16 * CHK; f += 256) {
            const int rc = f / CHK, g = f - rc * CHK;
            const int row = rg * 8 + (rc >> 4), ch = rc & 15;
            uint4 o = make_uint4(0u, 0u, 0u, 0u);
            if (g >= 1 && g <= 16) {
                const float4* s4 = (const float4*)(xn + ((size_t)ch * H + row) * W + (g - 1) * 8);
                float4 va = s4[0], vb = s4[1];
                o.x = pk_bf16(va.x, va.y); o.y = pk_bf16(va.z, va.w);
                o.z = pk_bf16(vb.x, vb.y); o.w = pk_bf16(vb.z, vb.w);
            }
            dst[((size_t)row * 16 + ch) * CHK + g] = o;
        }
        return;
    }
    const int b2 = b - 1024;
    const int n = b2 & 31, j = (b2 >> 5) & 15, zi = b2 >> 9;
    const float* x = zi ? x2 : x1;
    const float* y = zi ? y2 : y1;
    float* P       = zi ? P2 : P1;

    const float* yn = y + (size_t)n * H * W;
    const float* xc = x + ((size_t)n * C + j) * H * W;

    // 256 threads = 32 column-chunks (wg) x 8 row-slabs of 16 rows.
    const int wg = tid & 31, slab = tid >> 5;
    const int r0 = slab * 16;

    float acc[25];
#pragma unroll
    for (int l = 0; l < 25; ++l) acc[l] = 0.f;

    // rolling window: yw[u] = y[r + 2 - u] (float4 at columns wg*4..wg*4+3).
    float4 yw[5];
#pragma unroll
    for (int u = 0; u < 5; ++u) {
        const int t = r0 + 1 - u;
        yw[u] = (t >= 0) ? *(const float4*)(yn + (size_t)t * W + wg * 4)
                         : make_float4(0.f, 0.f, 0.f, 0.f);
    }

#pragma unroll 4
    for (int rr = 0; rr < 16; ++rr) {
        const int r = r0 + rr;
#pragma unroll
        for (int u = 4; u >= 1; --u) yw[u] = yw[u - 1];
        const int tnew = r + 2;
        yw[0] = (tnew < H) ? *(const float4*)(yn + (size_t)tnew * W + wg * 4)
                           : make_float4(0.f, 0.f, 0.f, 0.f);

        const float* xr = xc + (size_t)r * W + wg * 4;
        float w12[12];
        float4 t4 = (wg > 0) ? *(const float4*)(xr - 4) : make_float4(0, 0, 0, 0);
        w12[0] = t4.x; w12[1] = t4.y; w12[2] = t4.z; w12[3] = t4.w;
        t4 = *(const float4*)(xr);
        w12[4] = t4.x; w12[5] = t4.y; w12[6] = t4.z; w12[7] = t4.w;
        t4 = (wg < 31) ? *(const float4*)(xr + 4) : make_float4(0, 0, 0, 0);
        w12[8] = t4.x; w12[9] = t4.y; w12[10] = t4.z; w12[11] = t4.w;

#pragma unroll
        for (int u = 0; u < 5; ++u) {
#pragma unroll
            for (int v = 0; v < 5; ++v)
                acc[u * 5 + v] += yw[u].x * w12[2 + v] + yw[u].y * w12[3 + v] +
                                  yw[u].z * w12[4 + v] + yw[u].w * w12[5 + v];
        }
    }

    __shared__ float red[4][25];
    const int lane = tid & 63, wv = tid >> 6;
#pragma unroll
    for (int l = 0; l < 25; ++l) {
        float v = acc[l];
#pragma unroll
        for (int off = 32; off; off >>= 1) v += __shfl_down(v, off);
        if (lane == 0) red[wv][l] = v;
    }
    __syncthreads();
    if (tid < 25)
        P[((size_t)n * C + j) * 25 + tid] = red[0][tid] + red[1][tid] + red[2][tid] + red[3][tid];
}

// ---------------------------------------------------------------------------
// MFMA autocorr: grid (n, zi, ug:4), 512 threads (8 waves).
// ---------------------------------------------------------------------------
template<int P0, int P1>
__device__ __forceinline__ void autocorr_body(const unsigned short* __restrict__ xn,
                                              float* __restrict__ Rn,
                                              char* sm, int tid)
{
    constexpr int U0 = P0 / 9;
    constexpr int U1 = (P1 - 1) / 9;
    constexpr int NB = U1 - U0 + 1;
    constexpr int NP = P1 - P0;
    constexpr int SLOT_Q = SLOT_B / 16;      // 304 uint4 per row-slot

    unsigned short* ring = (unsigned short*)sm;
    const int lane = tid & 63;
    const int wid  = tid >> 6;
    const int q    = lane >> 4;
    const int mi   = lane & 15;
    const int rh   = wid & 3;
    const int chh  = wid >> 2;

    f32x4 acc[NP];
#pragma unroll
    for (int l = 0; l < NP; ++l) acc[l] = (f32x4){0.f, 0.f, 0.f, 0.f};

    const char* gb = (const char*)xn;

    for (int f = tid; f < 4 * SLOT_Q; f += 512)
        ((uint4*)sm)[(12 + f / SLOT_Q) * SLOT_Q + (f % SLOT_Q)] = make_uint4(0, 0, 0, 0);
    // initial stage: rows 0..7 -> slots 0..7; contiguous 8*4864 = 38912 B
    // in both global and LDS -> 38 wave-chunks of 1024 B (16B/lane).
    for (int f = wid; f < 38; f += 8)
        gl_lds16(gb + (size_t)f * 1024 + lane * 16, sm + f * 1024);
    __syncthreads();

    for (int s = 0; s < H; s += 4) {
        if (s < H - 8) {
            // prefetch rows s+8..s+11 -> slots (s+8..s+11)&15; the 4-slot
            // group is aligned & contiguous: 4*4864 = 19456 B = 19 chunks.
            const size_t gbase = (size_t)(s + 8) * SLOT_B;
            char* lbase = sm + ((s + 8) & 15) * SLOT_B;
            for (int f = wid; f < 19; f += 8)
                gl_lds16(gb + gbase + (size_t)f * 1024 + lane * 16, lbase + f * 1024);
        } else {
            for (int f = tid; f < 4 * SLOT_Q; f += 512)
                ((uint4*)sm)[(((s + 8 + f / SLOT_Q) & 15)) * SLOT_Q + (f % SLOT_Q)] = make_uint4(0, 0, 0, 0);
        }

        const int r = s + rh;
        const unsigned short* rowA = ring + (r & 15) * SLOT_U + mi * CH_U;
#pragma unroll
        for (int cc = 0; cc < 2; ++cc) {
            const int w0 = (chh * 2 + cc) * 32;
            const uint4* pa = (const uint4*)(rowA + w0 + 8 * q);
            uint4 A0 = pa[0], A1 = pa[1], A2 = pa[2];
            unsigned int d[12] = {A0.x, A0.y, A0.z, A0.w, A1.x, A1.y, A1.z, A1.w,
                                  A2.x, A2.y, A2.z, A2.w};
            short8 bf[NB];
#pragma unroll
            for (int u = U0; u <= U1; ++u)
                bf[u - U0] = *(const short8*)(ring + ((r + u - 4 + 16) & 15) * SLOT_U +
                                              mi * CH_U + 8 + w0 + 8 * q);
#pragma unroll
            for (int v = 0; v < 9; ++v) {
                const int off = 12 - v;
                const int q4  = off >> 1;
                union { unsigned int u4[4]; short8 s8; } af;
                if (off & 1) {
#pragma unroll
                    for (int k2 = 0; k2 < 4; ++k2)
                        af.u4[k2] = (d[q4 + k2] >> 16) | (d[q4 + k2 + 1] << 16);
                } else {
#pragma unroll
                    for (int k2 = 0; k2 < 4; ++k2) af.u4[k2] = d[q4 + k2];
                }
#pragma unroll
                for (int u = U0; u <= U1; ++u) {
                    if (u * 9 + v >= P0 && u * 9 + v < P1)
                        acc[u * 9 + v - P0] = __builtin_amdgcn_mfma_f32_16x16x32_bf16(
                            af.s8, bf[u - U0], acc[u * 9 + v - P0], 0, 0, 0);
                }
            }
        }
        __syncthreads();
    }

    float* sred = (float*)sm;
#pragma unroll
    for (int cb = 0; cb < NP; cb += 9) {
        const int nc = (NP - cb < 9) ? (NP - cb) : 9;
        __syncthreads();
#pragma unroll
        for (int pp = 0; pp < 9; ++pp) {
            if (pp < nc) {
#pragma unroll
                for (int rg = 0; rg < 4; ++rg)
                    sred[(pp * 8 + wid) * 256 + (q * 4 + rg) * 16 + mi] = acc[cb + pp][rg];
            }
        }
        __syncthreads();
        if (tid < 256) {
#pragma unroll
            for (int pp = 0; pp < 9; ++pp) {
                if (pp < nc) {
                    float ssum = 0.f;
#pragma unroll
                    for (int w8 = 0; w8 < 8; ++w8)
                        ssum += sred[(pp * 8 + w8) * 256 + tid];
                    Rn[(size_t)tid * NLAG + P0 + cb + pp] = ssum;
                }
            }
        }
    }
}

__global__ __launch_bounds__(512, 2)
void autocorr_mfma(const unsigned short* __restrict__ xb,
                   float* __restrict__ R1, float* __restrict__ R2)
{
    __shared__ __align__(16) char sm[RING_B];
    const int n = blockIdx.x, zi = blockIdx.y, ug = blockIdx.z;
    const unsigned short* xn = xb + (size_t)zi * XB_US_PER_IN + (size_t)n * H * SLOT_U;
    float* Rn = (zi ? R2 : R1) + (size_t)n * C * C * NLAG;
    switch (ug) {
        case 0:  autocorr_body< 0, 20>(xn, Rn, sm, threadIdx.x); break;
        case 1:  autocorr_body<20, 40>(xn, Rn, sm, threadIdx.x); break;
        case 2:  autocorr_body<40, 60>(xn, Rn, sm, threadIdx.x); break;
        default: autocorr_body<60, 81>(xn, Rn, sm, threadIdx.x); break;
    }
}

// ---------------------------------------------------------------------------
// fused solve: CG1 (3 it) + CG2 (7 it) + 6-layer CNN, one block per sample.
// ---------------------------------------------------------------------------
__device__ __forceinline__ float block_sum512(float v, float* red, int tid)
{
#pragma unroll
    for (int off = 32; off; off >>= 1) v += __shfl_down(v, off);
    if ((tid & 63) == 0) red[tid >> 6] = v;
    __syncthreads();
    float s = red[0] + red[1] + red[2] + red[3] + red[4] + red[5] + red[6] + red[7];
    __syncthreads();
    return s;
}

__device__ __forceinline__ float cg_solve(const float* __restrict__ Rrow, float rhs,
                                          int iters, float a, int t,
                                          float* pv, float* ap, float* red)
{
    const int jj = t & 15;
    float zreg = 0.f, rreg = 0.f, pmine = 0.f;
    if (t < M) {
        rreg = rhs; pmine = rhs;
        pv[(t / 25) * 28 + (t % 25)] = rhs;
    }
    float rr = block_sum512((t < M) ? rreg * rreg : 0.f, red, t);

    for (int it = 0; it < iters; ++it) {
        if (t < 256) {
            float pld[25], acc[25];
            const float* pj = &pv[jj * 28];
#pragma unroll
            for (int k = 0; k < 25; ++k) pld[k] = pj[k];
#pragma unroll
            for (int k = 0; k < 25; ++k) acc[k] = 0.f;
#pragma unroll
            for (int u = 0; u < 9; ++u) {
#pragma unroll
                for (int v = 0; v < 9; ++v) {
                    const float Rv = Rrow[u * 9 + v];      // LDS scalar read
#pragma unroll
                    for (int c = 0; c < 5; ++c) {
                        if (c < u - 4 || c > u) continue;
                        const int aa = 4 + c - u;
#pragma unroll
                        for (int dd = 0; dd < 5; ++dd) {
                            if (dd < v - 4 || dd > v) continue;
                            const int bb = 4 + dd - v;
                            acc[aa * 5 + bb] += Rv * pld[c * 5 + dd];
                        }
                    }
                }
            }
#pragma unroll
            for (int k = 0; k < 25; ++k) {
                float s2 = acc[k];
                s2 += __shfl_down(s2, 8, 16);
                s2 += __shfl_down(s2, 4, 16);
                s2 += __shfl_down(s2, 2, 16);
                s2 += __shfl_down(s2, 1, 16);
                acc[k] = s2;
            }
            if (jj == 0) {
#pragma unroll
                for (int k = 0; k < 25; ++k) ap[(t >> 4) * 25 + k] = acc[k];
            }
        }
        __syncthreads();
        float apv = 0.f;
        if (t < M) apv = ap[t] + a * pmine;
        float pAp = block_sum512((t < M) ? pmine * apv : 0.f, red, t);
        float al  = (pAp > 1e-30f) ? rr / pAp : 0.f;
        if (t < M) { zreg += al * pmine; rreg -= al * apv; }
        float rrn = block_sum512(rreg * rreg, red, t);
        float be  = (rr > 1e-30f) ? rrn / rr : 0.f;
        rr = rrn;
        if (t < M) {
            pmine = rreg + be * pmine;
            pv[(t / 25) * 28 + (t % 25)] = pmine;
        }
        __syncthreads();
    }
    return zreg;
}

__global__ __launch_bounds__(512, 1)
void solve_kernel(const float* __restrict__ R1, const float* __restrict__ R2,
                  const float* __restrict__ P1, const float* __restrict__ P2,
                  const float* __restrict__ d0, const float* __restrict__ alpha,
                  const float* __restrict__ beta, const float* __restrict__ reg,
                  const float* __restrict__ w1, const float* __restrict__ b1,
                  const float* __restrict__ w2, const float* __restrict__ b2,
                  const float* __restrict__ w3, const float* __restrict__ b3,
                  const float* __restrict__ w4, const float* __restrict__ b4,
                  const float* __restrict__ w5, const float* __restrict__ b5,
                  const float* __restrict__ w6, const float* __restrict__ b6,
                  float* __restrict__ out)
{
    __shared__ __align__(16) float Rl[256 * NLAG];   // 82944 B
    __shared__ float pv[16 * 28];
    __shared__ float ap[M];
    __shared__ float red[8];
    __shared__ float h0p[25 * 20];
    __shared__ float bufA[25 * 20], bufB[25 * 20];
    __shared__ float wl[16 * 9 * 20];
    __shared__ float bl[16];

    const int n = blockIdx.x, t = threadIdx.x;
    const float a = alpha[n] * (float)(H * W) * reg[0] / (float)(DS * DS * C);

    // stage R1 -> LDS (flat linear, async dma)
    {
        const char* g = (const char*)(R1 + (size_t)n * 256 * NLAG);
        char* l = (char*)Rl;
        for (int f = t; f < 256 * NLAG / 4; f += 512)
            gl_lds16(g + (size_t)f * 16, l + (size_t)f * 16);
    }
    float rhs1 = 0.f;
    if (t < M) rhs1 = P1[(size_t)n * M + t] + a * d0[(size_t)n * M + t];
    __syncthreads();   // drains the DMA
    float z1 = cg_solve(&Rl[(t & 255) * NLAG], rhs1, 3, a, t, pv, ap, red);

    __syncthreads();   // all reads of Rl done
    {
        const char* g = (const char*)(R2 + (size_t)n * 256 * NLAG);
        char* l = (char*)Rl;
        for (int f = t; f < 256 * NLAG / 4; f += 512)
            gl_lds16(g + (size_t)f * 16, l + (size_t)f * 16);
    }
    float rhs2 = 0.f;
    if (t < M) rhs2 = P2[(size_t)n * M + t] + a * z1;
    __syncthreads();
    float z2 = cg_solve(&Rl[(t & 255) * NLAG], rhs2, 7, a, t, pv, ap, red);

    // ---- CNN. Activations [pix][ch] pitch 20; weights [o*9+kk][ci] pitch 20.
    if (t < M) h0p[(t % 25) * 20 + t / 25] = z2;
    if (t < 25) h0p[t * 20 + 16] = rsqrtf(beta[n]);
    __syncthreads();

    const float* wsl[6] = {w1, w2, w3, w4, w5, w6};
    const float* bsl[6] = {b1, b2, b3, b4, b5, b6};

    for (int l = 0; l < 6; ++l) {
        const int cin = (l == 0) ? 17 : 16;
        for (int f = t; f < 16 * cin * 9; f += 512) {
            const int o = f / (cin * 9);
            const int rm = f - o * cin * 9;
            const int ci = rm / 9, kk = rm - ci * 9;
            wl[(o * 9 + kk) * 20 + ci] = wsl[l][f];
        }
        if (t < 16) bl[t] = bsl[l][t];
        __syncthreads();

        const float* act = (l == 0) ? h0p : ((l & 1) ? bufA : bufB);
        float s = 0.f;
        if (t < 400) {
            const int o = t / 25, pix = t % 25, yy = pix / 5, xx = pix % 5;
            s = bl[o];
#pragma unroll
            for (int ky = 0; ky < 3; ++ky) {
                const int iy = yy + ky - 1;
                if ((unsigned)iy >= 5u) continue;
#pragma unroll
                for (int kx = 0; kx < 3; ++kx) {
                    const int ix = xx + kx - 1;
                    if ((unsigned)ix >= 5u) continue;
                    const float* ip = act + (iy * 5 + ix) * 20;
                    const float* wp = wl + (o * 9 + ky * 3 + kx) * 20;
                    const float4 a0 = *(const float4*)(ip);
                    const float4 a1 = *(const float4*)(ip + 4);
                    const float4 a2 = *(const float4*)(ip + 8);
                    const float4 a3 = *(const float4*)(ip + 12);
                    const float4 q0 = *(const float4*)(wp);
                    const float4 q1 = *(const float4*)(wp + 4);
                    const float4 q2 = *(const float4*)(wp + 8);
                    const float4 q3 = *(const float4*)(wp + 12);
                    s += a0.x * q0.x + a0.y * q0.y + a0.z * q0.z + a0.w * q0.w
                       + a1.x * q1.x + a1.y * q1.y + a1.z * q1.z + a1.w * q1.w
                       + a2.x * q2.x + a2.y * q2.y + a2.z * q2.z + a2.w * q2.w
                       + a3.x * q3.x + a3.y * q3.y + a3.z * q3.z + a3.w * q3.w;
                    if (l == 0) s += ip[16] * wp[16];
                }
            }
            if (l < 5) s = fmaxf(s, 0.f);
            else       s += h0p[(t % 25) * 20 + t / 25];
        }
        __syncthreads();
        if (t < 400) {
            if (l == 5) out[(size_t)n * M + t] = s;
            else {
                float* dstb = (l & 1) ? bufB : bufA;
                dstb[(t % 25) * 20 + t / 25] = s;
            }
        }
        __syncthreads();
    }
}

// ---------------------------------------------------------------------------
extern "C" void kernel_launch(void* const* d_in, const int* in_sizes, int n_in,
                              void* d_out, int out_size, void* d_ws, size_t ws_size,
                              hipStream_t stream)
{
    (void)in_sizes; (void)n_in; (void)out_size; (void)ws_size;
    const float* x1    = (const float*)d_in[0];
    const float* x2    = (const float*)d_in[1];
    const float* d0    = (const float*)d_in[2];
    const float* y1    = (const float*)d_in[3];
    const float* y2    = (const float*)d_in[4];
    const float* alpha = (const float*)d_in[5];
    const float* beta  = (const float*)d_in[6];
    const float* reg   = (const float*)d_in[7];
    const float* w1 = (const float*)d_in[8];  const float* b1 = (const float*)d_in[9];
    const float* w2 = (const float*)d_in[10]; const float* b2 = (const float*)d_in[11];
    const float* w3 = (const float*)d_in[12]; const float* b3 = (const float*)d_in[13];
    const float* w4 = (const float*)d_in[14]; const float* b4 = (const float*)d_in[15];
    const float* w5 = (const float*)d_in[16]; const float* b5 = (const float*)d_in[17];
    const float* w6 = (const float*)d_in[18]; const float* b6 = (const float*)d_in[19];
    float* out = (float*)d_out;

    char* wsb = (char*)d_ws;
    unsigned short* xb = (unsigned short*)wsb;                 // ~40 MB
    float* R1 = (float*)(wsb + 2 * XB_US_PER_IN * 2);
    const size_t RSZ = (size_t)NS * C * C * NLAG;              // 663552 floats
    float* R2 = R1 + RSZ;
    float* P1 = R2 + RSZ;
    float* P2 = P1 + (size_t)NS * M;

    prep_kernel<<<2048, 256, 0, stream>>>(x1, x2, y1, y2, xb, P1, P2);
    autocorr_mfma<<<dim3(NS, 2, 4), 512, 0, stream>>>(xb, R1, R2);
    solve_kernel<<<NS, 512, 0, stream>>>(R1, R2, P1, P2, d0, alpha, beta, reg,
                                         w1, b1, w2, b2, w3, b3, w4, b4,
                                         w5, b5, w6, b6, out);
}